// Round 1
// baseline (112.751 us; speedup 1.0000x reference)
//
#include <hip/hip_runtime.h>
#include <hip/hip_bf16.h>
#include <math.h>

#define TD 512      // D (feature dim)
#define TH 64       // H (hidden dim)
#define CHUNK 64    // rows per chunk
#define NT 512      // threads per block (8 waves)

typedef __attribute__((ext_vector_type(8))) short bf16x8;
typedef __attribute__((ext_vector_type(4))) float f32x4;

__device__ __forceinline__ unsigned short f2b(float f) {
    unsigned u = __builtin_bit_cast(unsigned, f);
    u = u + 0x7FFFu + ((u >> 16) & 1u);   // round-to-nearest-even
    return (unsigned short)(u >> 16);
}

__device__ __forceinline__ float tanh_fast(float v) {
    // tanh(x) = 1 - 2/(e^{2x}+1); robust for +-inf ranges
    float e = __expf(2.0f * v);
    return 1.0f - 2.0f / (e + 1.0f);
}

__global__ __launch_bounds__(NT, 1)
void attnpool_kernel(const float* __restrict__ x,
                     const float* __restrict__ W1,
                     const float* __restrict__ b1,
                     const float* __restrict__ W2,
                     const float* __restrict__ b2,
                     const int* __restrict__ batch32,
                     float* __restrict__ out,
                     int N)
{
    __shared__ __align__(16) unsigned short W1T[TH * TD];   // bf16 bits, [col][k], XOR-swizzled
    __shared__ __align__(16) unsigned short Atile[CHUNK * TD]; // bf16 bits, [row][k], XOR-swizzled
    __shared__ float sP[4][CHUNK];
    __shared__ float sbuf[CHUNK];
    __shared__ float wbuf[CHUNK];
    __shared__ float outbuf[TD];
    __shared__ float b1s[TH];
    __shared__ float W2s[TH];
    __shared__ float mstate[4];   // 0: m_run, 1: l_run, 2: m_new, 3: alpha

    const int tid  = threadIdx.x;
    const int b    = blockIdx.x;
    const int lane = tid & 63;
    const int w    = tid >> 6;

    // ---- stage W1 -> bf16, transposed [col][k] with 16B XOR swizzle ----
    for (int i = 0; i < (TH * TD) / NT; ++i) {
        int e = tid + NT * i;          // flat index into W1 [k][j]
        int k = e >> 6;                // 0..511
        int j = e & 63;                // 0..63
        unsigned short v = f2b(W1[e]);
        int idx = (j * TD + k) ^ ((j & 7) << 3);   // elem-granularity swizzle (8 elems = 16B)
        W1T[idx] = v;
    }
    if (tid < TH) { b1s[tid] = b1[tid]; W2s[tid] = W2[tid]; }
    if (tid == 0) { mstate[0] = -INFINITY; mstate[1] = 0.0f; }
    const float b2v = b2[0];

    // ---- batch dtype detection (int64 vs int32) + segment bounds ----
    bool is64 = (batch32[N - 1] == 0);   // int64 little-endian => last word is a high word == 0
    auto bval = [&](int i) -> int { return is64 ? batch32[2 * i] : batch32[i]; };
    int lo = 0, hi = N;
    while (lo < hi) { int mid = (lo + hi) >> 1; if (bval(mid) < b) lo = mid + 1; else hi = mid; }
    const int seg_start = lo;
    hi = N;
    while (lo < hi) { int mid = (lo + hi) >> 1; if (bval(mid) < b + 1) lo = mid + 1; else hi = mid; }
    const int seg_len = lo - seg_start;

    const int rowcls = tid >> 7;          // 0..3 (row class within chunk)
    const int col4   = (tid & 127) << 2;  // feature column base (x4)
    const int ct     = w >> 1;            // coltile 0..3 (16 cols each)
    const int rt0    = (w & 1) << 1;      // rowtile base (0 or 2)

    float4 accw; accw.x = 0.f; accw.y = 0.f; accw.z = 0.f; accw.w = 0.f;
    float4 xrA[16], xrB[16];

    auto load_chunk = [&](float4 (&xr)[16], int c0) {
        #pragma unroll
        for (int p = 0; p < 16; ++p) {
            int rl = (p << 2) + rowcls;
            int r  = c0 + rl;
            int gr = (r < seg_len) ? (seg_start + r) : seg_start;  // clamp (w=0 kills pads)
            xr[p] = *reinterpret_cast<const float4*>(&x[(size_t)gr * TD + col4]);
        }
    };

    auto body = [&](float4 (&cur)[16], float4 (&nxt)[16], int c0) {
        // phase 2: convert + store A tile (swizzled)
        #pragma unroll
        for (int p = 0; p < 16; ++p) {
            int rl = (p << 2) + rowcls;
            ushort4 v;
            v.x = f2b(cur[p].x); v.y = f2b(cur[p].y);
            v.z = f2b(cur[p].z); v.w = f2b(cur[p].w);
            int idx = (rl * TD + col4) ^ ((rl & 7) << 3);
            *reinterpret_cast<ushort4*>(&Atile[idx]) = v;
        }
        __syncthreads();
        // prefetch next chunk's x into the other register buffer
        if (c0 + CHUNK < seg_len) load_chunk(nxt, c0 + CHUNK);

        // phase 3: MFMA  (wave covers rowtiles rt0, rt0+1 x coltile ct, full K)
        f32x4 acc0 = {0,0,0,0}, acc1 = {0,0,0,0};
        {
            const int rA = (rt0 << 4) + (lane & 15);
            const int rB = rA + 16;
            const int cc = (ct << 4) + (lane & 15);
            const int kb = (lane >> 4) << 3;
            #pragma unroll
            for (int kk = 0; kk < 16; ++kk) {
                int k0 = (kk << 5) + kb;
                bf16x8 bf = *reinterpret_cast<const bf16x8*>(&W1T[(cc * TD + k0) ^ ((cc & 7) << 3)]);
                bf16x8 a0 = *reinterpret_cast<const bf16x8*>(&Atile[(rA * TD + k0) ^ ((rA & 7) << 3)]);
                bf16x8 a1 = *reinterpret_cast<const bf16x8*>(&Atile[(rB * TD + k0) ^ ((rB & 7) << 3)]);
                acc0 = __builtin_amdgcn_mfma_f32_16x16x32_bf16(a0, bf, acc0, 0, 0, 0);
                acc1 = __builtin_amdgcn_mfma_f32_16x16x32_bf16(a1, bf, acc1, 0, 0, 0);
            }
        }
        // phase 4: bias + tanh + *W2, reduce over this wave's 16 cols
        {
            const int j = (ct << 4) + (lane & 15);
            float pa[4], pb[4];
            #pragma unroll
            for (int q = 0; q < 4; ++q) {
                pa[q] = tanh_fast(acc0[q] + b1s[j]) * W2s[j];
                pb[q] = tanh_fast(acc1[q] + b1s[j]) * W2s[j];
            }
            #pragma unroll
            for (int m = 1; m < 16; m <<= 1) {
                #pragma unroll
                for (int q = 0; q < 4; ++q) {
                    pa[q] += __shfl_xor(pa[q], m, 64);
                    pb[q] += __shfl_xor(pb[q], m, 64);
                }
            }
            if ((lane & 15) == 0) {
                int g = lane >> 4;
                #pragma unroll
                for (int q = 0; q < 4; ++q) {
                    sP[ct][(rt0 << 4) + (g << 2) + q]       = pa[q];
                    sP[ct][((rt0 + 1) << 4) + (g << 2) + q] = pb[q];
                }
            }
        }
        __syncthreads();

        // phase 5: online softmax update (wave 0 only computes; all read)
        if (tid < CHUNK) {
            int r = c0 + tid;
            float s = (r < seg_len)
                      ? (sP[0][tid] + sP[1][tid] + sP[2][tid] + sP[3][tid] + b2v)
                      : -INFINITY;
            sbuf[tid] = s;
            float mx = s;
            #pragma unroll
            for (int m = 1; m < 64; m <<= 1) mx = fmaxf(mx, __shfl_xor(mx, m, 64));
            if (tid == 0) {
                float mo = mstate[0];
                float mn = fmaxf(mo, mx);
                mstate[2] = mn;
                mstate[3] = __expf(mo - mn);   // alpha; mo=-inf -> 0
                mstate[0] = mn;
            }
        }
        __syncthreads();
        const float mn    = mstate[2];
        const float alpha = mstate[3];
        accw.x *= alpha; accw.y *= alpha; accw.z *= alpha; accw.w *= alpha;
        if (tid < CHUNK) {
            float e = __expf(sbuf[tid] - mn);   // -inf -> 0 for pad rows
            wbuf[tid] = e;
            float ls = e;
            #pragma unroll
            for (int m = 1; m < 64; m <<= 1) ls += __shfl_xor(ls, m, 64);
            if (tid == 0) mstate[1] = mstate[1] * alpha + ls;
        }
        __syncthreads();

        // phase 6: weighted accumulation straight from registers (fp32 x)
        #pragma unroll
        for (int p = 0; p < 16; ++p) {
            float wgt = wbuf[(p << 2) + rowcls];
            accw.x += wgt * cur[p].x;
            accw.y += wgt * cur[p].y;
            accw.z += wgt * cur[p].z;
            accw.w += wgt * cur[p].w;
        }
    };

    __syncthreads();   // W1T, b1s, W2s, mstate ready

    if (seg_len > 0) {
        load_chunk(xrA, 0);
        int c0 = 0;
        while (true) {
            body(xrA, xrB, c0);
            c0 += CHUNK;
            if (c0 >= seg_len) break;
            body(xrB, xrA, c0);
            c0 += CHUNK;
            if (c0 >= seg_len) break;
        }
    }

    // ---- epilogue: reduce accw across the 4 row classes, normalize, store ----
    for (int g = 0; g < 4; ++g) {
        if (rowcls == g) {
            if (g == 0) {
                outbuf[col4 + 0] = accw.x; outbuf[col4 + 1] = accw.y;
                outbuf[col4 + 2] = accw.z; outbuf[col4 + 3] = accw.w;
            } else {
                outbuf[col4 + 0] += accw.x; outbuf[col4 + 1] += accw.y;
                outbuf[col4 + 2] += accw.z; outbuf[col4 + 3] += accw.w;
            }
        }
        __syncthreads();
    }
    float inv = 1.0f / (mstate[1] + 1e-16f);
    out[(size_t)b * TD + tid] = outbuf[tid] * inv;
}

extern "C" void kernel_launch(void* const* d_in, const int* in_sizes, int n_in,
                              void* d_out, int out_size, void* d_ws, size_t ws_size,
                              hipStream_t stream) {
    const float* x  = (const float*)d_in[0];
    const float* W1 = (const float*)d_in[1];
    const float* b1 = (const float*)d_in[2];
    const float* W2 = (const float*)d_in[3];
    const float* b2 = (const float*)d_in[4];
    const int* batch = (const int*)d_in[5];
    int N = in_sizes[5];
    int B = out_size / TD;
    if (B <= 0 || N <= 0) return;
    attnpool_kernel<<<dim3(B), dim3(NT), 0, stream>>>(
        x, W1, b1, W2, b2, batch, (float*)d_out, N);
}